// Round 1
// baseline (13703.708 us; speedup 1.0000x reference)
//
#include <hip/hip_runtime.h>
#include <hip/hip_bf16.h>

// Problem constants
#define E_   256
#define H_   512
#define T_   512
#define B_   128
#define TBE_ (T_*B_*E_)

typedef __attribute__((ext_vector_type(4))) float  f32x4;
typedef __attribute__((ext_vector_type(8))) __bf16 bf16x8;
typedef __attribute__((ext_vector_type(8))) short  short8;

// ---- workspace layout (bytes, all 256-aligned) ----
#define OFF_WA   256                        // packed stage-A gate weights [2][1536][768] bf16 (cols 0:512=Wc, 512:768=W0f)
#define SZ_WA    (2*1536*768*2)
#define OFF_WY   (OFF_WA + SZ_WA)           // y weights (lin_W) [256][512] bf16 (shared by branches)
#define SZ_WY    (256*512*2)
#define OFF_WB   (OFF_WY + SZ_WY)           // packed stage-B weights [2][1536][512] bf16
#define SZ_WB    (2*1536*512*2)
#define OFF_BA0  (OFF_WB + SZ_WB)           // stage-A bias, t==0 variant [2][1536] f32
#define OFF_BA1  (OFF_BA0 + 2*1536*4)       // stage-A bias, t>0 variant (includes W0p@lin_b)
#define OFF_BBv  (OFF_BA1 + 2*1536*4)       // stage-B bias [2][1536] f32
#define OFF_XA   (OFF_BBv + 2*1536*4)       // h1 state [2][128][512] bf16
#define OFF_XB   (OFF_XA + 2*B_*H_*2)       // h0 state [2][128][512] bf16
#define WS_NEED  (OFF_XB + 2*B_*H_*2)       // ~8.7 MB

#define NWG 80              // 2 branches x (32 gate WGs + 8 y WGs)
#define LDS_BYTES 122880    // 48*1536 (stage-A slice) + 48*1024 (stage-B slice)

__device__ __host__ inline int gate_src_row(int p) {
  // packed row p in [0,1536): w=p/48 slice, r=p%48: [0,16)=i, [16,32)=g, [32,48)=o
  int w = p / 48, r = p % 48;
  int grp = r >> 4;
  int idx = r & 15;
  int base = (grp == 0) ? 0 : (grp == 1 ? 1024 : 1536);
  return base + 16*w + idx;
}

__device__ inline unsigned short f2bf(float f) {   // RNE f32->bf16 (values are tame, no NaN handling)
  unsigned u = __float_as_uint(f);
  u += 0x7fffu + ((u >> 16) & 1u);
  return (unsigned short)(u >> 16);
}
__device__ inline float sigf(float x)      { return __builtin_amdgcn_rcpf(1.f + __expf(-x)); }
__device__ inline float tanh_fast(float x) { return 1.f - 2.f*__builtin_amdgcn_rcpf(1.f + __expf(2.f*x)); }

// ======================= weight packing =======================

// Wc = W0p @ lin_W  -> WA cols [0,512)
__global__ __launch_bounds__(256) void k_pack_wc(const float* __restrict__ uW0, const float* __restrict__ lW0,
                                                 const float* __restrict__ linW, unsigned short* __restrict__ WA) {
  int blk = blockIdx.x;                 // 2*1536 blocks
  int branch = blk / 1536, p = blk % 1536;
  const float* W0 = branch ? lW0 : uW0;
  int s = gate_src_row(p);
  __shared__ float a[256];
  int tid = threadIdx.x;
  a[tid] = W0[(size_t)s*512 + tid];     // W0p row (cols 0:256 = prev part)
  __syncthreads();
  for (int kk = 0; kk < 2; ++kk) {
    int k = kk*256 + tid;
    float acc = 0.f;
    #pragma unroll 8
    for (int e = 0; e < 256; ++e) acc = fmaf(a[e], linW[(size_t)e*512 + k], acc);
    WA[((size_t)branch*1536 + p)*768 + k] = f2bf(acc);
  }
}

// feat-part of WA, all of WB, all biases
__global__ __launch_bounds__(256) void k_pack_rest(
    const float* __restrict__ uW0, const float* __restrict__ ubi0, const float* __restrict__ ubh0,
    const float* __restrict__ uW1, const float* __restrict__ ubi1, const float* __restrict__ ubh1,
    const float* __restrict__ lW0, const float* __restrict__ lbi0, const float* __restrict__ lbh0,
    const float* __restrict__ lW1, const float* __restrict__ lbi1, const float* __restrict__ lbh1,
    const float* __restrict__ linb,
    unsigned short* __restrict__ WA, unsigned short* __restrict__ WB,
    float* __restrict__ bA0, float* __restrict__ bA1, float* __restrict__ bBv) {
  int blk = blockIdx.x;
  int branch = blk / 1536, p = blk % 1536;
  const float* W0  = branch ? lW0  : uW0;
  const float* bi0 = branch ? lbi0 : ubi0;
  const float* bh0 = branch ? lbh0 : ubh0;
  const float* W1  = branch ? lW1  : uW1;
  const float* bi1 = branch ? lbi1 : ubi1;
  const float* bh1 = branch ? lbh1 : ubh1;
  int s = gate_src_row(p);
  int tid = threadIdx.x;
  size_t rowA = (size_t)branch*1536 + p;
  WA[rowA*768 + 512 + tid]  = f2bf(W0[(size_t)s*512 + 256 + tid]);   // W0f
  WB[rowA*512 + tid]        = f2bf(W1[(size_t)s*512 + tid]);
  WB[rowA*512 + 256 + tid]  = f2bf(W1[(size_t)s*512 + 256 + tid]);
  __shared__ float red[256];
  red[tid] = W0[(size_t)s*512 + tid] * linb[tid];   // c0 = W0p @ lin_b
  __syncthreads();
  for (int st = 128; st > 0; st >>= 1) { if (tid < st) red[tid] += red[tid + st]; __syncthreads(); }
  if (tid == 0) {
    float b0 = bi0[s] + bh0[s];
    bA0[rowA] = b0;
    bA1[rowA] = b0 + red[0];
    bBv[rowA] = bi1[s] + bh1[s];
  }
}

__global__ __launch_bounds__(256) void k_pack_wy(const float* __restrict__ linW, unsigned short* __restrict__ WY) {
  int i = blockIdx.x*256 + threadIdx.x;
  if (i < 256*512) WY[i] = f2bf(linW[i]);
}

// ======================= persistent recurrent kernel =======================

__device__ inline void grid_barrier(unsigned int* bar, unsigned int target) {
  __syncthreads();
  if (threadIdx.x == 0) {
    __hip_atomic_fetch_add(bar, 1u, __ATOMIC_RELEASE, __HIP_MEMORY_SCOPE_AGENT);
    for (;;) {
      unsigned int v = __hip_atomic_load(bar, __ATOMIC_RELAXED, __HIP_MEMORY_SCOPE_AGENT);
      if (v >= target) break;
      __builtin_amdgcn_s_sleep(1);
    }
    (void)__hip_atomic_load(bar, __ATOMIC_ACQUIRE, __HIP_MEMORY_SCOPE_AGENT);  // L1/L2 inv
  }
  __syncthreads();
}

__global__ __launch_bounds__(256) void k_rnn(
    const float* __restrict__ featU, const float* __restrict__ featL,
    const float* __restrict__ linb,
    float* __restrict__ out, unsigned char* __restrict__ ws) {

  extern __shared__ unsigned char lds[];
  const int bid    = blockIdx.x;
  const int branch = bid / 40;
  const int role   = bid % 40;
  const bool isGate = role < 32;
  const int w = isGate ? role : (role - 32);
  const float* feat = branch ? featL : featU;

  unsigned short* WA  = (unsigned short*)(ws + OFF_WA) + (size_t)branch*1536*768;
  unsigned short* WY  = (unsigned short*)(ws + OFF_WY);
  unsigned short* WBp = (unsigned short*)(ws + OFF_WB) + (size_t)branch*1536*512;
  const float* bA0 = (const float*)(ws + OFF_BA0) + branch*1536;
  const float* bA1 = (const float*)(ws + OFF_BA1) + branch*1536;
  const float* bBv = (const float*)(ws + OFF_BBv) + branch*1536;
  unsigned short* xA = (unsigned short*)(ws + OFF_XA) + (size_t)branch*B_*H_;   // h1 state
  unsigned short* xB = (unsigned short*)(ws + OFF_XB) + (size_t)branch*B_*H_;   // h0 state
  unsigned int* bar = (unsigned int*)ws;

  const int tid = threadIdx.x;
  const int l   = tid & 63;
  const int wv  = tid >> 6;   // wave 0..3
  const int lg  = l >> 4;     // k-group 0..3
  const int ln  = l & 15;     // row/col in tile

  // ---- stage weights into LDS (XOR-swizzled: addr ^ ((row&7)<<4)) ----
  if (isGate) {
    const unsigned short* srcA = WA + (size_t)(48*w)*768;
    for (int c = tid; c < 48*96; c += 256) {           // 16B chunks, 96/row
      int r = c / 96, c16 = c % 96;
      uint4 v = *(const uint4*)(srcA + (size_t)r*768 + c16*8);
      *(uint4*)(lds + ((r*1536 + c16*16) ^ ((r & 7) << 4))) = v;
    }
    const unsigned short* srcB = WBp + (size_t)(48*w)*512;
    for (int c = tid; c < 48*64; c += 256) {
      int r = c / 64, c16 = c % 64;
      uint4 v = *(const uint4*)(srcB + (size_t)r*512 + c16*8);
      *(uint4*)(lds + 73728 + ((r*1024 + c16*16) ^ ((r & 7) << 4))) = v;
    }
  } else {
    const unsigned short* srcY = WY + (size_t)(32*w)*512;
    for (int c = tid; c < 32*64; c += 256) {
      int r = c / 64, c16 = c % 64;
      uint4 v = *(const uint4*)(srcY + (size_t)r*512 + c16*8);
      *(uint4*)(lds + ((r*1024 + c16*16) ^ ((r & 7) << 4))) = v;
    }
  }

  // ---- per-lane bias preload (constant-indexed -> registers) ----
  float ba0[12], ba1[12], bbv[12], by[8];
  if (isGate) {
    #pragma unroll
    for (int mt = 0; mt < 3; ++mt)
      #pragma unroll
      for (int rg = 0; rg < 4; ++rg) {
        int p = 48*w + mt*16 + 4*lg + rg;
        ba0[mt*4+rg] = bA0[p];
        ba1[mt*4+rg] = bA1[p];
        bbv[mt*4+rg] = bBv[p];
      }
  } else {
    #pragma unroll
    for (int mt = 0; mt < 2; ++mt)
      #pragma unroll
      for (int rg = 0; rg < 4; ++rg)
        by[mt*4+rg] = linb[32*w + mt*16 + 4*lg + rg];
  }
  __syncthreads();

  const f32x4 zv = {0.f, 0.f, 0.f, 0.f};
  unsigned int phase = 0;

  for (int t = 0; t < T_; ++t) {
    // ================= stage A: gates0 -> h0 (gate WGs), y_{t-1} (y WGs) =================
    if (isGate) {
      f32x4 acc[3][2];
      #pragma unroll
      for (int mt = 0; mt < 3; ++mt) { acc[mt][0] = zv; acc[mt][1] = zv; }

      if (t > 0) {                       // Wc part: k in [0,512) from h1 state
        for (int kt = 0; kt < 16; ++kt) {
          short8 bfr[2];
          #pragma unroll
          for (int nt = 0; nt < 2; ++nt) {
            int n = (wv*2 + nt)*16 + ln;
            bfr[nt] = *(const short8*)(xA + (size_t)n*H_ + kt*32 + 8*lg);
          }
          #pragma unroll
          for (int mt = 0; mt < 3; ++mt) {
            int r = mt*16 + ln;
            short8 afr = *(const short8*)(lds + ((r*1536 + kt*64 + 16*lg) ^ ((r & 7) << 4)));
            #pragma unroll
            for (int nt = 0; nt < 2; ++nt)
              acc[mt][nt] = __builtin_amdgcn_mfma_f32_16x16x32_bf16(
                  __builtin_bit_cast(bf16x8, afr), __builtin_bit_cast(bf16x8, bfr[nt]),
                  acc[mt][nt], 0, 0, 0);
          }
        }
      }
      for (int kt = 16; kt < 24; ++kt) { // feat part: k in [512,768)
        short8 bfr[2];
        #pragma unroll
        for (int nt = 0; nt < 2; ++nt) {
          int n = (wv*2 + nt)*16 + ln;
          const float* pf = feat + ((size_t)n*T_ + t)*E_ + (kt-16)*32 + 8*lg;
          float4 f0 = *(const float4*)pf;
          float4 f1 = *(const float4*)(pf + 4);
          short8 b;
          b[0]=(short)f2bf(f0.x); b[1]=(short)f2bf(f0.y); b[2]=(short)f2bf(f0.z); b[3]=(short)f2bf(f0.w);
          b[4]=(short)f2bf(f1.x); b[5]=(short)f2bf(f1.y); b[6]=(short)f2bf(f1.z); b[7]=(short)f2bf(f1.w);
          bfr[nt] = b;
        }
        #pragma unroll
        for (int mt = 0; mt < 3; ++mt) {
          int r = mt*16 + ln;
          short8 afr = *(const short8*)(lds + ((r*1536 + kt*64 + 16*lg) ^ ((r & 7) << 4)));
          #pragma unroll
          for (int nt = 0; nt < 2; ++nt)
            acc[mt][nt] = __builtin_amdgcn_mfma_f32_16x16x32_bf16(
                __builtin_bit_cast(bf16x8, afr), __builtin_bit_cast(bf16x8, bfr[nt]),
                acc[mt][nt], 0, 0, 0);
        }
      }
      // activation (i,g,o -> h0) + store h0 slice
      float bcur[12];
      #pragma unroll
      for (int q = 0; q < 12; ++q) bcur[q] = (t == 0) ? ba0[q] : ba1[q];
      #pragma unroll
      for (int nt = 0; nt < 2; ++nt) {
        int bcol = (wv*2 + nt)*16 + ln;
        unsigned short hp[4];
        #pragma unroll
        for (int rg = 0; rg < 4; ++rg) {
          float iv = acc[0][nt][rg] + bcur[rg];
          float gv = acc[1][nt][rg] + bcur[4+rg];
          float ov = acc[2][nt][rg] + bcur[8+rg];
          float c  = sigf(iv) * tanh_fast(gv);
          float h  = sigf(ov) * tanh_fast(c);
          hp[rg] = f2bf(h);
        }
        ushort4 st; st.x = hp[0]; st.y = hp[1]; st.z = hp[2]; st.w = hp[3];
        *(ushort4*)(xB + (size_t)bcol*H_ + 16*w + 4*lg) = st;
      }
    } else if (t > 0) {                  // y WGs: y_{t-1} = h1_{t-1} @ lin_W.T + lin_b
      f32x4 acc[2][2];
      acc[0][0]=zv; acc[0][1]=zv; acc[1][0]=zv; acc[1][1]=zv;
      for (int kt = 0; kt < 16; ++kt) {
        short8 bfr[2];
        #pragma unroll
        for (int nt = 0; nt < 2; ++nt) {
          int n = (wv*2 + nt)*16 + ln;
          bfr[nt] = *(const short8*)(xA + (size_t)n*H_ + kt*32 + 8*lg);
        }
        #pragma unroll
        for (int mt = 0; mt < 2; ++mt) {
          int r = mt*16 + ln;
          short8 afr = *(const short8*)(lds + ((r*1024 + kt*64 + 16*lg) ^ ((r & 7) << 4)));
          #pragma unroll
          for (int nt = 0; nt < 2; ++nt)
            acc[mt][nt] = __builtin_amdgcn_mfma_f32_16x16x32_bf16(
                __builtin_bit_cast(bf16x8, afr), __builtin_bit_cast(bf16x8, bfr[nt]),
                acc[mt][nt], 0, 0, 0);
        }
      }
      #pragma unroll
      for (int mt = 0; mt < 2; ++mt)
        #pragma unroll
        for (int nt = 0; nt < 2; ++nt) {
          int bcol = (wv*2 + nt)*16 + ln;
          float4 o;
          o.x = acc[mt][nt][0] + by[mt*4+0];
          o.y = acc[mt][nt][1] + by[mt*4+1];
          o.z = acc[mt][nt][2] + by[mt*4+2];
          o.w = acc[mt][nt][3] + by[mt*4+3];
          *(float4*)(out + (size_t)branch*TBE_ + ((size_t)(t-1)*B_ + bcol)*E_ + 32*w + mt*16 + 4*lg) = o;
        }
    }
    ++phase; grid_barrier(bar, phase*NWG);

    // ================= stage B: gates1 -> h1 =================
    if (isGate) {
      f32x4 acc[3][2];
      #pragma unroll
      for (int mt = 0; mt < 3; ++mt) { acc[mt][0] = zv; acc[mt][1] = zv; }
      for (int kt = 0; kt < 16; ++kt) {
        short8 bfr[2];
        #pragma unroll
        for (int nt = 0; nt < 2; ++nt) {
          int n = (wv*2 + nt)*16 + ln;
          bfr[nt] = *(const short8*)(xB + (size_t)n*H_ + kt*32 + 8*lg);
        }
        #pragma unroll
        for (int mt = 0; mt < 3; ++mt) {
          int r = mt*16 + ln;
          short8 afr = *(const short8*)(lds + 73728 + ((r*1024 + kt*64 + 16*lg) ^ ((r & 7) << 4)));
          #pragma unroll
          for (int nt = 0; nt < 2; ++nt)
            acc[mt][nt] = __builtin_amdgcn_mfma_f32_16x16x32_bf16(
                __builtin_bit_cast(bf16x8, afr), __builtin_bit_cast(bf16x8, bfr[nt]),
                acc[mt][nt], 0, 0, 0);
        }
      }
      #pragma unroll
      for (int nt = 0; nt < 2; ++nt) {
        int bcol = (wv*2 + nt)*16 + ln;
        unsigned short hp[4];
        #pragma unroll
        for (int rg = 0; rg < 4; ++rg) {
          float iv = acc[0][nt][rg] + bbv[rg];
          float gv = acc[1][nt][rg] + bbv[4+rg];
          float ov = acc[2][nt][rg] + bbv[8+rg];
          float c  = sigf(iv) * tanh_fast(gv);
          float h  = sigf(ov) * tanh_fast(c);
          hp[rg] = f2bf(h);
        }
        ushort4 st; st.x = hp[0]; st.y = hp[1]; st.z = hp[2]; st.w = hp[3];
        *(ushort4*)(xA + (size_t)bcol*H_ + 16*w + 4*lg) = st;
      }
    }
    ++phase; grid_barrier(bar, phase*NWG);
  }

  // ================= final y_{T-1} =================
  if (!isGate) {
    f32x4 acc[2][2];
    acc[0][0]=zv; acc[0][1]=zv; acc[1][0]=zv; acc[1][1]=zv;
    for (int kt = 0; kt < 16; ++kt) {
      short8 bfr[2];
      #pragma unroll
      for (int nt = 0; nt < 2; ++nt) {
        int n = (wv*2 + nt)*16 + ln;
        bfr[nt] = *(const short8*)(xA + (size_t)n*H_ + kt*32 + 8*lg);
      }
      #pragma unroll
      for (int mt = 0; mt < 2; ++mt) {
        int r = mt*16 + ln;
        short8 afr = *(const short8*)(lds + ((r*1024 + kt*64 + 16*lg) ^ ((r & 7) << 4)));
        #pragma unroll
        for (int nt = 0; nt < 2; ++nt)
          acc[mt][nt] = __builtin_amdgcn_mfma_f32_16x16x32_bf16(
              __builtin_bit_cast(bf16x8, afr), __builtin_bit_cast(bf16x8, bfr[nt]),
              acc[mt][nt], 0, 0, 0);
      }
    }
    #pragma unroll
    for (int mt = 0; mt < 2; ++mt)
      #pragma unroll
      for (int nt = 0; nt < 2; ++nt) {
        int bcol = (wv*2 + nt)*16 + ln;
        float4 o;
        o.x = acc[mt][nt][0] + by[mt*4+0];
        o.y = acc[mt][nt][1] + by[mt*4+1];
        o.z = acc[mt][nt][2] + by[mt*4+2];
        o.w = acc[mt][nt][3] + by[mt*4+3];
        *(float4*)(out + (size_t)branch*TBE_ + ((size_t)(T_-1)*B_ + bcol)*E_ + 32*w + mt*16 + 4*lg) = o;
      }
  }
}

// ======================= launch =======================

extern "C" void kernel_launch(void* const* d_in, const int* in_sizes, int n_in,
                              void* d_out, int out_size, void* d_ws, size_t ws_size,
                              hipStream_t stream) {
  (void)in_sizes; (void)n_in; (void)out_size; (void)ws_size;
  const float* upF  = (const float*)d_in[0];
  const float* loF  = (const float*)d_in[1];
  const float* uW0  = (const float*)d_in[2];
  const float* ubi0 = (const float*)d_in[3];
  const float* ubh0 = (const float*)d_in[4];
  const float* uW1  = (const float*)d_in[5];
  const float* ubi1 = (const float*)d_in[6];
  const float* ubh1 = (const float*)d_in[7];
  const float* lW0  = (const float*)d_in[8];
  const float* lbi0 = (const float*)d_in[9];
  const float* lbh0 = (const float*)d_in[10];
  const float* lW1  = (const float*)d_in[11];
  const float* lbi1 = (const float*)d_in[12];
  const float* lbh1 = (const float*)d_in[13];
  const float* linW = (const float*)d_in[14];
  const float* linb = (const float*)d_in[15];
  float* out = (float*)d_out;
  unsigned char* ws = (unsigned char*)d_ws;

  unsigned short* WA  = (unsigned short*)(ws + OFF_WA);
  unsigned short* WY  = (unsigned short*)(ws + OFF_WY);
  unsigned short* WB  = (unsigned short*)(ws + OFF_WB);
  float* bA0 = (float*)(ws + OFF_BA0);
  float* bA1 = (float*)(ws + OFF_BA1);
  float* bBv = (float*)(ws + OFF_BBv);

  hipMemsetAsync(d_ws, 0, 256, stream);   // zero barrier counter

  k_pack_wc<<<dim3(2*1536), dim3(256), 0, stream>>>(uW0, lW0, linW, WA);
  k_pack_rest<<<dim3(2*1536), dim3(256), 0, stream>>>(uW0, ubi0, ubh0, uW1, ubi1, ubh1,
                                                      lW0, lbi0, lbh0, lW1, lbi1, lbh1,
                                                      linb, WA, WB, bA0, bA1, bBv);
  k_pack_wy<<<dim3(512), dim3(256), 0, stream>>>(linW, WY);

  hipFuncSetAttribute((const void*)k_rnn, hipFuncAttributeMaxDynamicSharedMemorySize, LDS_BYTES);
  k_rnn<<<dim3(NWG), dim3(256), LDS_BYTES, stream>>>(upF, loF, linb, out, ws);
}